// Round 17
// baseline (164.310 us; speedup 1.0000x reference)
//
#include <hip/hip_runtime.h>
#include <hip/hip_bf16.h>

typedef float f32x4 __attribute__((ext_vector_type(4)));
typedef short bf16x8 __attribute__((ext_vector_type(8)));
typedef unsigned short us8 __attribute__((ext_vector_type(8)));
typedef unsigned short us4 __attribute__((ext_vector_type(4)));

__device__ __forceinline__ unsigned short f2bf(float f) {
  union { float f; unsigned u; } v; v.f = f;
  return (unsigned short)((v.u + 0x8000u) >> 16);   // round-half-up bf16
}
__device__ __forceinline__ float bf2f(unsigned short u) {
  union { unsigned u; float f; } v; v.u = ((unsigned)u) << 16;
  return v.f;
}

// ---------------------------------------------------------------------------
// Kernel 1: VmatT[b][n][p] (bf16), n = c*16+u*4+v (256), p = pi*64+pj (4096)
// ---------------------------------------------------------------------------
__global__ __launch_bounds__(256) void prep_vmat(const float* __restrict__ x,
                                                 unsigned short* __restrict__ vmatT) {
  int t = blockIdx.x * 256 + threadIdx.x;
  int pc = t & 511;
  int n  = (t >> 9) & 255;
  int b  = t >> 17;
  int c = n >> 4, u = (n >> 2) & 3, v = n & 3;
  int pi = pc >> 3;
  int pj0 = (pc & 7) << 3;
  int row = 2 * pi + u - 1;
  row = row < 0 ? 0 : (row > 127 ? 127 : row);
  const float* xr = x + ((size_t)(b * 16 + c) * 128 + row) * 128;
  us8 o;
#pragma unroll
  for (int e = 0; e < 8; ++e) {
    int col = 2 * (pj0 + e) + v - 1;
    col = col < 0 ? 0 : (col > 127 ? 127 : col);
    o[e] = f2bf(xr[col]);
  }
  *reinterpret_cast<us8*>(vmatT + (size_t)t * 8) = o;
}

// ---------------------------------------------------------------------------
// Kernel 2: A[b][q][n] (bf16) = sum_p scores[b][q][p] * VmatT[b][n][p]
// R13 deep-FIFO discipline at BK=128 -> 32 iters (half of R13's 64).
// Rationale: R10 (2x iters -> +107us) / R13 (deeper FIFO -> -17us) / R14
// (deeper still -> null) isolate a ~1360 cyc/iter FIXED convoy cost on top
// of the co-saturated HBM(3120)/LDS(~3330) floors; halving iteration count
// attacks it directly. R11's BK=128 failed for occupancy (4 waves/CU);
// this keeps 8 waves (512 thr) + single wait/iter + counted vmcnt.
//  - 8 waves M-split (16 q-rows each), BQ=128, 32 K-tiles of 128.
//  - LDS: B ring-2 x 64 KB = 128 KB. 16-slot XOR swizzle (R11's):
//    source gs=(c&15)^((c>>4)&15), read pos=((ks*4+l16)^l15)*8.
//  - A: per-lane direct frags, 2-deep (rE/rO, 8 f32x4 = 64 VGPR total);
//    CONV extracts all 4 fa frags BEFORE the reload.
//  - per iter: CONV; STAGE_B(kt+1)[8]; LOAD_A(kt+2)[8]; 64 MFMA;
//    vmcnt(8) drains A(kt+1)+B(kt+1), leaves A(kt+2)=64 KB/CU riding the
//    barrier; B(kt+1) covered by the ~6000-cyc MFMA phase.
//  - ring-2 WAR: buf (kt+1)&1 written at kt, last read kt-1 (barrier between).
//  - uniform 32 iters; tail wraps (&31) kept alive by trailing asm.
// ---------------------------------------------------------------------------
__global__ __launch_bounds__(512, 2) void gemm_scores_vmat(
    const float* __restrict__ scores,
    const unsigned short* __restrict__ vmatT,
    unsigned short* __restrict__ Amat) {
  __shared__ unsigned short ldsB[2][32768];   // 2 x (256 rows x 128 bf16)

  int bid = blockIdx.x;                        // 256 blocks = 1/CU
  int batch = bid & 7;                         // = XCD id
  int qb = (bid >> 3) << 7;                    // 32 q-blocks of 128
  const int phase = (bid >> 3) & 31;

  const int t = threadIdx.x;
  const int lane = t & 63;
  const int wq = t >> 6;                       // wave id 0..7 = M slice
  const int l15 = lane & 15, l16 = lane >> 4;

  // A: per-lane fragment base (row = qb + wq*16 + l15, k-offset l16*8)
  const float* aLane =
      scores + ((size_t)(batch * 4096 + qb + wq * 16 + l15)) * 4096 + l16 * 8;
  const unsigned short* Vb = vmatT + (size_t)batch * 256 * 4096;

  // B staging: 4096 chunks of 16 B / tile; thread t takes c = t + i*512.
  // row = c>>4, slot = c&15, source slot pre-swizzled gs = slot ^ (row&15).
  const unsigned short* bSrc[8];
#pragma unroll
  for (int i = 0; i < 8; ++i) {
    int c = t + i * 512;
    int gs = (c & 15) ^ ((c >> 4) & 15);
    bSrc[i] = Vb + (size_t)(c >> 4) * 4096 + gs * 8;
  }

  f32x4 acc[16];
#pragma unroll
  for (int ni = 0; ni < 16; ++ni) acc[ni] = (f32x4){0.f, 0.f, 0.f, 0.f};

  f32x4 rE[8], rO[8];     // two named A sets (tile = 4 frags = 8 f32x4)
  bf16x8 fa[4];

#define SB __builtin_amdgcn_sched_barrier(0)
#define STAGE_B(kt, bufi)                                                     \
  {                                                                           \
    int kp_ = ((kt) + phase) & 31;                                            \
    _Pragma("unroll") for (int i = 0; i < 8; ++i)                             \
        __builtin_amdgcn_global_load_lds(                                     \
            (const __attribute__((address_space(1))) void*)(bSrc[i] + (size_t)kp_ * 128), \
            (__attribute__((address_space(3))) void*)&ldsB[bufi][(t + i * 512) * 8], \
            16, 0, 0);                                                        \
  }
#define LOAD_A(kt, rr)                                                        \
  {                                                                           \
    int kp_ = ((kt) + phase) & 31;                                            \
    const float* ap_ = aLane + (size_t)kp_ * 128;                             \
    rr[0] = *(const f32x4*)(ap_);                                             \
    rr[1] = *(const f32x4*)(ap_ + 4);                                         \
    rr[2] = *(const f32x4*)(ap_ + 32);                                        \
    rr[3] = *(const f32x4*)(ap_ + 36);                                        \
    rr[4] = *(const f32x4*)(ap_ + 64);                                        \
    rr[5] = *(const f32x4*)(ap_ + 68);                                        \
    rr[6] = *(const f32x4*)(ap_ + 96);                                        \
    rr[7] = *(const f32x4*)(ap_ + 100);                                       \
  }
#define CONV(rr)                                                              \
  {                                                                           \
    _Pragma("unroll") for (int f = 0; f < 4; ++f)                             \
        _Pragma("unroll") for (int e = 0; e < 4; ++e) {                       \
      fa[f][e]     = (short)f2bf(rr[2 * f][e]);                               \
      fa[f][e + 4] = (short)f2bf(rr[2 * f + 1][e]);                           \
    }                                                                         \
  }
#define MFMAS(bufi)                                                           \
  {                                                                           \
    _Pragma("unroll") for (int ks = 0; ks < 4; ++ks)                          \
        _Pragma("unroll") for (int ni = 0; ni < 16; ++ni) {                   \
      int pos = ((ks * 4 + l16) ^ l15) << 3;                                  \
      bf16x8 bv = *(const bf16x8*)(&ldsB[bufi][0] +                           \
                                   (ni * 16 + l15) * 128 + pos);              \
      acc[ni] = __builtin_amdgcn_mfma_f32_16x16x32_bf16(fa[ks], bv, acc[ni],  \
                                                        0, 0, 0);             \
    }                                                                         \
  }
// iter kt (buf = kt&1, A set rr): consume A(kt)+B(kt)
#define BODY(b_, kt, rr)                                                      \
  {                                                                           \
    CONV(rr);                   /* extract BEFORE reload */                   \
    SB;                                                                       \
    STAGE_B((kt) + 1, (b_) ^ 1);                                              \
    SB;                                                                       \
    LOAD_A((kt) + 2, rr);                                                     \
    SB;                                                                       \
    MFMAS(b_);                                                                \
    SB;                                                                       \
    asm volatile("s_waitcnt vmcnt(8)" ::: "memory");                          \
    SB;                                                                       \
    __builtin_amdgcn_s_barrier();                                             \
    SB;                                                                       \
  }

  // ---- prologue: B(0)[8], A(0)[8], A(1)[8]; vmcnt(8) drains B0+A0,
  // leaves A(1) in flight (steady-state entry).
  STAGE_B(0, 0);
  SB;
  LOAD_A(0, rE);
  SB;
  LOAD_A(1, rO);
  SB;
  asm volatile("s_waitcnt vmcnt(8)" ::: "memory");
  SB;
  __builtin_amdgcn_s_barrier();
  SB;

  // ---- main loop: 32 uniform iters, unrolled x2 (static reg-set roles)
  for (int kt = 0; kt < 32; kt += 2) {
    BODY(0, kt, rE);
    BODY(1, kt + 1, rO);
  }

  // keep tail wrap prefetches live so the vmcnt FIFO accounting stays exact
  asm volatile("" ::"v"(rE[0][0]), "v"(rE[3][0]), "v"(rE[5][0]), "v"(rE[7][0]),
               "v"(rO[0][0]), "v"(rO[3][0]), "v"(rO[5][0]), "v"(rO[7][0]));

#undef SB
#undef STAGE_B
#undef LOAD_A
#undef CONV
#undef MFMAS
#undef BODY

  // C-write: wave wq owns q-rows qb+wq*16..+15; row=(l16*4+j), col=l15 per ni
  unsigned short* Ao = Amat + ((size_t)(batch * 4096 + qb + wq * 16)) * 256;
#pragma unroll
  for (int ni = 0; ni < 16; ++ni)
#pragma unroll
    for (int j = 0; j < 4; ++j)
      Ao[(size_t)(l16 * 4 + j) * 256 + ni * 16 + l15] = f2bf(acc[ni][j]);
}

// ---------------------------------------------------------------------------
// Kernel 3: coalesced LDS-staged epilogue (R16, -10.6 us vs scattered).
// ---------------------------------------------------------------------------
__global__ __launch_bounds__(256) void epilogue_kernel(
    const float* __restrict__ x, const unsigned short* __restrict__ Amat,
    const float* __restrict__ alpha, float* __restrict__ out) {
  __shared__ unsigned short L[2 * 64 * 66];   // plane p, row j, col cv (c*4+v)

  int b = blockIdx.x >> 7;
  int h = blockIdx.x & 127;
  int t = threadIdx.x;

  int ihi = (h + 1) >> 1, u_hi = (h + 1) & 1;
  bool p0ok = (ihi <= 63), p1ok = (ihi >= 1);
  const unsigned short* Ab = Amat + (size_t)b * 4096 * 256;

  unsigned int* Lw = reinterpret_cast<unsigned int*>(L);
#pragma unroll
  for (int p = 0; p < 2; ++p) {
    bool ok = p ? p1ok : p0ok;
    int rbase = (p ? (ihi - 1) : ihi) * 64;
    int u = u_hi + 2 * p;
#pragma unroll
    for (int i = 0; i < 4; ++i) {
      int q = t + 256 * i;
      int j = q >> 4, c = q & 15;
      us4 ch = (us4){0, 0, 0, 0};
      if (ok)
        ch = *reinterpret_cast<const us4*>(Ab + (size_t)(rbase + j) * 256 +
                                           c * 16 + u * 4);
      int widx = (p * 4224 + j * 66 + c * 4) >> 1;
      Lw[widx]     = (unsigned int)(unsigned short)ch[0] |
                     ((unsigned int)(unsigned short)ch[1] << 16);
      Lw[widx + 1] = (unsigned int)(unsigned short)ch[2] |
                     ((unsigned int)(unsigned short)ch[3] << 16);
    }
  }
  __syncthreads();

  int w = t & 127;
  int cg = t >> 7;
  int jhi = (w + 1) >> 1, v_hi = (w + 1) & 1;
  bool vj_hi = (jhi <= 63), vj_lo = (jhi >= 1);
  float al = alpha[0] * 0.25f;

#pragma unroll
  for (int cc = 0; cc < 8; ++cc) {
    int c = cg * 8 + cc;
    float s = 0.f;
    if (vj_hi) {
      int o = jhi * 66 + c * 4 + v_hi;
      s += bf2f(L[o]) + bf2f(L[4224 + o]);
    }
    if (vj_lo) {
      int o = (jhi - 1) * 66 + c * 4 + v_hi + 2;
      s += bf2f(L[o]) + bf2f(L[4224 + o]);
    }
    size_t xi = (((size_t)b * 16 + c) * 128 + h) * 128 + w;
    out[xi] = x[xi] + al * s;
  }
}

extern "C" void kernel_launch(void* const* d_in, const int* in_sizes, int n_in,
                              void* d_out, int out_size, void* d_ws, size_t ws_size,
                              hipStream_t stream) {
  const float* x      = (const float*)d_in[0];
  const float* scores = (const float*)d_in[1];
  const float* alpha  = (const float*)d_in[2];
  float* out = (float*)d_out;

  unsigned short* vmatT = (unsigned short*)d_ws;
  unsigned short* Amat  = (unsigned short*)((char*)d_ws + (size_t)16 * 1024 * 1024);

  prep_vmat<<<4096, 256, 0, stream>>>(x, vmatT);
  gemm_scores_vmat<<<256, 512, 0, stream>>>(scores, vmatT, Amat);
  epilogue_kernel<<<1024, 256, 0, stream>>>(x, Amat, alpha, out);
}